// Round 30
// baseline (105.482 us; speedup 1.0000x reference)
//
#include <hip/hip_runtime.h>

#define T_STEPS 2000
#define B_DIM 16
#define L_DIM 1024

// FitzHugh-Nagumo Euler — matched to the XLA-compiled f32 reference (the
// harness RUNS the jax code: `jaxref_precompute_s` in bench timing). XLA:
// pow(v,3) -> (v*v)*v ; elementwise chain contracted by LLVM DAGCombiner:
//   t2 = c3 * v3
//   a1 = fma(1.1f, v, -t2)        [visitFSUB: lhs-mul rule fires FIRST]
//   a2 = fma(-0.1f, s, a1)        [lhs now fma -> rhs-mul rule]
//   vn = fma(0.1f, z, a2)         [visitFADD: rhs-mul rule]
//   u3 = fma(-0.8f, s, v + 0.7f)
//   s' = fma(0.008f, u3, s)
//   out = 0.5f*vn ; row 0 = 0
// R1 tested the WRONG innermost fusion (fma(-c3,v3,1.1*v)) = 0.533; all
// non-contracted f32 schedules = 0.530 (R2=R26 basin). This DAGCombiner
// pattern is the one XLA actually emits; IEEE fma is bitwise identical on
// x86 FMA3 and gfx950 v_fma_f32. All ops asm-pinned (flag-proof).
__device__ __forceinline__ float vmulf(float a, float b) {
    float d; asm("v_mul_f32 %0, %1, %2" : "=v"(d) : "v"(a), "v"(b)); return d;
}
__device__ __forceinline__ float vaddf(float a, float b) {
    float d; asm("v_add_f32 %0, %1, %2" : "=v"(d) : "v"(a), "v"(b)); return d;
}
__device__ __forceinline__ float vfma(float a, float b, float c) {
    float d; asm("v_fma_f32 %0, %1, %2, %3" : "=v"(d) : "v"(a), "v"(b), "v"(c)); return d;
}
__device__ __forceinline__ float vfma_negc(float a, float b, float c) {   // a*b - c
    float d; asm("v_fma_f32 %0, %1, %2, -%3" : "=v"(d) : "v"(a), "v"(b), "v"(c)); return d;
}
__device__ __forceinline__ float vfma_nega(float a, float b, float c) {   // -a*b + c
    float d; asm("v_fma_f32 %0, -%1, %2, %3" : "=v"(d) : "v"(a), "v"(b), "v"(c)); return d;
}

__global__ __launch_bounds__(64, 1) void fh_kernel(const float* __restrict__ z,
                                                   float* __restrict__ out) {
    const float C_1P = (float)(1.0 + 0.1);   // f32(1.1)
    const float C_3  = (float)(0.1 / 3.0);   // 0.033333335f
    const float C_DT = 0.1f;
    const float C_SK = (float)(0.1 * 0.08);  // 0.008f
    const float C_07 = 0.7f;
    const float C_08 = 0.8f;

    const int idx = blockIdx.x * 64 + threadIdx.x;   // 0..16383
    const int b = idx >> 10;
    const int l = idx & 1023;
    const size_t base = (size_t)b * T_STEPS * L_DIM + l;
    const float* zp = z + base;
    float* outp = out + base;

    constexpr int STEPS = T_STEPS - 1;        // 1999 updates
    constexpr int D = 32;                     // prefetch ring depth
    constexpr int FULL = (STEPS / D) * D;     // 1984
    constexpr int TAIL = STEPS - FULL;        // 15

    float v = 0.0f, s = 0.0f;                 // pure f32 carries

    outp[0] = 0.0f;                           // k = 0 row
    outp += L_DIM;

    float ring[D];
#pragma unroll
    for (int i = 0; i < D; ++i)
        ring[i] = zp[(size_t)i * L_DIM];

    for (int c = 0; c < FULL; c += D) {
#pragma unroll
        for (int i = 0; i < D; ++i) {
            const float zk = ring[i];
            int pf = c + D + i;               // prefetch for step pf
            pf = pf < STEPS ? pf : STEPS - 1; // clamp (tail chunk only)
            ring[i] = zp[(size_t)pf * L_DIM];

            const float v3 = vmulf(vmulf(v, v), v);   // XLA: pow->(v*v)*v
            const float t2 = vmulf(C_3, v3);
            const float a1 = vfma_negc(C_1P, v, t2);  // fma(1.1,v,-t2)
            const float a2 = vfma_nega(C_DT, s, a1);  // fma(-dt,s,a1)
            const float vn = vfma(C_DT, zk, a2);      // fma(dt,z,a2)

            const float u1 = vaddf(v, C_07);          // OLD v
            const float u3 = vfma_nega(C_08, s, u1);  // fma(-0.8,s,u1)
            s = vfma(C_SK, u3, s);                    // fma(0.008,u3,s)
            v = vn;
            __builtin_nontemporal_store(vmulf(0.5f, v), outp);
            outp += L_DIM;
        }
    }

#pragma unroll
    for (int i = 0; i < TAIL; ++i) {
        const float zk = ring[i];

        const float v3 = vmulf(vmulf(v, v), v);
        const float t2 = vmulf(C_3, v3);
        const float a1 = vfma_negc(C_1P, v, t2);
        const float a2 = vfma_nega(C_DT, s, a1);
        const float vn = vfma(C_DT, zk, a2);

        const float u1 = vaddf(v, C_07);
        const float u3 = vfma_nega(C_08, s, u1);
        s = vfma(C_SK, u3, s);
        v = vn;
        __builtin_nontemporal_store(vmulf(0.5f, v), outp);
        outp += L_DIM;
    }
}

extern "C" void kernel_launch(void* const* d_in, const int* in_sizes, int n_in,
                              void* d_out, int out_size, void* d_ws, size_t ws_size,
                              hipStream_t stream) {
    const float* z = (const float*)d_in[0];
    float* out = (float*)d_out;
    const int total = B_DIM * L_DIM;          // 16384 independent chains
    dim3 grid(total / 64);                    // 256 blocks -> 1 wave per CU
    dim3 block(64);
    hipLaunchKernelGGL(fh_kernel, grid, block, 0, stream, z, out);
}

// Round 31
// 84.625 us; speedup vs baseline: 1.2465x; 1.2465x over previous
//
#include <hip/hip_runtime.h>

#define T_STEPS 2000
#define B_DIM 16
#define L_DIM 1024

// FitzHugh-Nagumo Euler — BIT-EXACT match to the XLA-compiled f32 jax ref
// (PROVEN R30: absmax == 0.0). Arithmetic (asm-pinned, flag-proof):
//   v3 = (v*v)*v ; t2 = c3*v3
//   a1 = fma(1.1f, v, -t2) ; a2 = fma(-0.1f, s, a1) ; vn = fma(0.1f, z, a2)
//   u1 = v + 0.7f ; u3 = fma(-0.8f, s, u1) ; s' = fma(0.008f, u3, s)
//   out = 0.5f*vn ; row 0 = 0
// R31 perf changes (arithmetic untouched): prefetch ring D 32->64 (4 MB in
// flight across 256 waves — 2x HBM-latency headroom vs the marginal D=32),
// clamp-free main chunks (steps 0..1919), single clamped chunk, 15-step tail.
__device__ __forceinline__ float vmulf(float a, float b) {
    float d; asm("v_mul_f32 %0, %1, %2" : "=v"(d) : "v"(a), "v"(b)); return d;
}
__device__ __forceinline__ float vaddf(float a, float b) {
    float d; asm("v_add_f32 %0, %1, %2" : "=v"(d) : "v"(a), "v"(b)); return d;
}
__device__ __forceinline__ float vfma(float a, float b, float c) {
    float d; asm("v_fma_f32 %0, %1, %2, %3" : "=v"(d) : "v"(a), "v"(b), "v"(c)); return d;
}
__device__ __forceinline__ float vfma_negc(float a, float b, float c) {   // a*b - c
    float d; asm("v_fma_f32 %0, %1, %2, -%3" : "=v"(d) : "v"(a), "v"(b), "v"(c)); return d;
}
__device__ __forceinline__ float vfma_nega(float a, float b, float c) {   // -a*b + c
    float d; asm("v_fma_f32 %0, -%1, %2, %3" : "=v"(d) : "v"(a), "v"(b), "v"(c)); return d;
}

__global__ __launch_bounds__(64, 1) void fh_kernel(const float* __restrict__ z,
                                                   float* __restrict__ out) {
    const float C_1P = (float)(1.0 + 0.1);   // f32(1.1)
    const float C_3  = (float)(0.1 / 3.0);   // 0.033333335f
    const float C_DT = 0.1f;
    const float C_SK = (float)(0.1 * 0.08);  // 0.008f
    const float C_07 = 0.7f;
    const float C_08 = 0.8f;

    const int idx = blockIdx.x * 64 + threadIdx.x;   // 0..16383
    const int b = idx >> 10;
    const int l = idx & 1023;
    const size_t base = (size_t)b * T_STEPS * L_DIM + l;
    const float* zp = z + base;
    float* outp = out + base;

    constexpr int STEPS = T_STEPS - 1;        // 1999 updates
    constexpr int D = 64;                     // prefetch ring depth
    constexpr int SAFE = 1920;                // chunks c<1920: pf<=1983<STEPS
    constexpr int TAIL = STEPS - 1984;        // 15

    float v = 0.0f, s = 0.0f;                 // pure f32 carries

    outp[0] = 0.0f;                           // k = 0 row
    outp += L_DIM;

    float ring[D];
#pragma unroll
    for (int i = 0; i < D; ++i)
        ring[i] = zp[(size_t)i * L_DIM];

#define FH_STEP(ZK)                                            \
    do {                                                       \
        const float v3 = vmulf(vmulf(v, v), v);                \
        const float t2 = vmulf(C_3, v3);                       \
        const float a1 = vfma_negc(C_1P, v, t2);               \
        const float a2 = vfma_nega(C_DT, s, a1);               \
        const float vn = vfma(C_DT, (ZK), a2);                 \
        const float u1 = vaddf(v, C_07);                       \
        const float u3 = vfma_nega(C_08, s, u1);               \
        s = vfma(C_SK, u3, s);                                 \
        v = vn;                                                \
        __builtin_nontemporal_store(vmulf(0.5f, v), outp);     \
        outp += L_DIM;                                         \
    } while (0)

    // main chunks: steps 0..1919, prefetch unclamped (pf = c+D+i <= 1983)
    for (int c = 0; c < SAFE; c += D) {
        const float* zpf = zp + (size_t)(c + D) * L_DIM;
#pragma unroll
        for (int i = 0; i < D; ++i) {
            const float zk = ring[i];
            ring[i] = zpf[(size_t)i * L_DIM];
            FH_STEP(zk);
        }
    }

    // clamped chunk: steps 1920..1983, prefetch pf = 1984+i clamped to 1998
    {
        const float* zpf = zp + (size_t)(SAFE + D) * L_DIM;
#pragma unroll
        for (int i = 0; i < D; ++i) {
            const float zk = ring[i];
            const int io = (i < TAIL) ? i : (TAIL - 1);   // pf <= 1998
            ring[i] = zpf[(size_t)io * L_DIM];
            FH_STEP(zk);
        }
    }

    // tail: steps 1984..1998 (no prefetch)
#pragma unroll
    for (int i = 0; i < TAIL; ++i) {
        const float zk = ring[i];
        FH_STEP(zk);
    }
#undef FH_STEP
}

extern "C" void kernel_launch(void* const* d_in, const int* in_sizes, int n_in,
                              void* d_out, int out_size, void* d_ws, size_t ws_size,
                              hipStream_t stream) {
    const float* z = (const float*)d_in[0];
    float* out = (float*)d_out;
    const int total = B_DIM * L_DIM;          // 16384 independent chains
    dim3 grid(total / 64);                    // 256 blocks -> 1 wave per CU
    dim3 block(64);
    hipLaunchKernelGGL(fh_kernel, grid, block, 0, stream, z, out);
}